// Round 3
// baseline (2183.378 us; speedup 1.0000x reference)
//
#include <hip/hip_runtime.h>
#include <stdint.h>

typedef _Float16 half8 __attribute__((ext_vector_type(8)));  // 8 fp16 (4 VGPR) MFMA frag
typedef __attribute__((ext_vector_type(4))) float f4;        // fp32x4 accum
typedef __attribute__((ext_vector_type(4))) unsigned int u32x4;
typedef __attribute__((ext_vector_type(2))) unsigned int u32x2;

#define LDAH 200   // halves per LDS A row (192 data + 8 pad; 100 words -> 2-way max, 16B aligned)
#define EXS  36    // exchange stride (floats); 144B row: 16B-aligned for f4 reads
#define HSTR 40    // sH stride (halves), 80B: 16B-aligned

__device__ __forceinline__ float sigm(float x) { return 1.0f / (1.0f + __expf(-x)); }
__device__ __forceinline__ float tanh_(float x) { return 1.0f - 2.0f / (__expf(2.0f * x) + 1.0f); } // overflow-safe

// ---------------- prologue kernels ----------------

// W_catA[2048][576] = [W_ih | W_hh] fp16 ; also W_ih part of W_catB
extern "C" __global__ void __launch_bounds__(256) k_wcat(
    const float* __restrict__ Wih, const float* __restrict__ Whh,
    _Float16* __restrict__ WA, _Float16* __restrict__ WB)
{
    int idx = blockIdx.x * 256 + threadIdx.x;        // grid 4608 -> exactly 2048*576
    int n = idx / 576, k = idx % 576;
    float v = (k < 64) ? Wih[n * 64 + k] : Whh[n * 512 + (k - 64)];
    _Float16 b = (_Float16)v;
    WA[idx] = b;
    if (k < 64) WB[idx] = b;
}

// W_catB[n][64+k] = W_hh[n][k] + sum_p W_ih[n][p] * W_out[p][k]   (fp32 accum, fp16 store)
extern "C" __global__ void __launch_bounds__(256) k_comb(
    const float* __restrict__ Wih, const float* __restrict__ Whh,
    const float* __restrict__ Wo, _Float16* __restrict__ WB)
{
    int bx = blockIdx.x;                             // grid 4096
    int n = bx >> 1;
    int kh = ((bx & 1) << 8) + threadIdx.x;          // 0..511
    float acc = Whh[n * 512 + kh];
    #pragma unroll 16
    for (int p = 0; p < 64; ++p)
        acc += Wih[n * 64 + p] * Wo[p * 512 + kh];
    WB[n * 576 + 64 + kh] = (_Float16)acc;
}

// Wout fp16, bias0 = b_ih+b_hh, bias1 = bias0 + W_ih@b_out, y_{-1} init (fp32 + fp16 hi/lo, both parities)
extern "C" __global__ void __launch_bounds__(256) k_misc(
    const float* __restrict__ Wo, const float* __restrict__ bih, const float* __restrict__ bhh,
    const float* __restrict__ Wih, const float* __restrict__ bo, const float* __restrict__ x,
    _Float16* __restrict__ WoB, float* __restrict__ b0v, float* __restrict__ b1v,
    float* __restrict__ yf0, float* __restrict__ yf1,
    _Float16* __restrict__ yh0, _Float16* __restrict__ yh1,
    _Float16* __restrict__ yl0, _Float16* __restrict__ yl1)
{
    int idx = blockIdx.x * 256 + threadIdx.x;        // grid 392
    if (idx < 32768) { WoB[idx] = (_Float16)Wo[idx]; return; }
    if (idx < 34816) {
        int n = idx - 32768;
        float b = bih[n] + bhh[n];
        b0v[n] = b;
        float a = b;
        #pragma unroll 16
        for (int p = 0; p < 64; ++p) a += Wih[n * 64 + p] * bo[p];
        b1v[n] = a;
        return;
    }
    if (idx < 100352) {
        int e = idx - 34816;
        int m = e >> 6, nn = e & 63;
        float v = x[m * 2048 + 31 * 64 + nn];        // x[:, -1, :]
        yf0[e] = v; yf1[e] = v;
        _Float16 hi = (_Float16)v;
        _Float16 lo = (_Float16)(v - (float)hi);
        yh0[e] = hi; yh1[e] = hi;
        yl0[e] = lo; yl1[e] = lo;
    }
}

// h0 = z @ Wproj^T + b_proj ; c0 = h0 ; h stored fp16 hi/lo
extern "C" __global__ void __launch_bounds__(256) k_h0(
    const float* __restrict__ z, const float* __restrict__ Wp, const float* __restrict__ bp,
    float* __restrict__ cst, _Float16* __restrict__ hh0, _Float16* __restrict__ hl0)
{
    int bx = blockIdx.x;                             // grid 2048
    int m = bx >> 1;
    int n = ((bx & 1) << 8) + threadIdx.x;
    float acc = bp[n];
    const f4* zr = (const f4*)&z[m * 128];           // block-uniform (scalar loads)
    const f4* wr = (const f4*)&Wp[n * 128];
    #pragma unroll 8
    for (int p = 0; p < 32; ++p) {
        f4 zv = zr[p], wv = wr[p];
        acc += zv[0]*wv[0] + zv[1]*wv[1] + zv[2]*wv[2] + zv[3]*wv[3];
    }
    cst[m * 512 + n] = acc;
    _Float16 hi = (_Float16)acc;
    hh0[m * 512 + n] = hi;
    hl0[m * 512 + n] = (_Float16)(acc - (float)hi);
}

// ---------------- per-step kernel ----------------
// grid 256 = 16 mt x 16 s, 512 threads (8 waves -> 2 waves/SIMD for latency hiding).
// block (mt, s): rows m0..m0+64, h-cols j0..j0+32 (all 4 gate quadrants).
// wave w: quadrant q=w>>1, col-half hx=w&1 -> 16 gate cols; acc[4] m-tiles.
// B loaded once per col (feeds hi-A AND lo-A MFMAs), double-buffered in regs across chunks.
// Post-GEMM operands (cst, bias, Wout frag) prefetched at head; y-resolve moved to tail.
// t in [0,128]; t==128 -> resolution of y_127 only.

__device__ __forceinline__ void resolve_y(
    int t, int row, int c4,
    const float* __restrict__ yf_in, float* __restrict__ yf_out,
    const float* __restrict__ dl_in, const float* __restrict__ bout,
    _Float16* __restrict__ yh_out, _Float16* __restrict__ yl_out,
    float* __restrict__ out)
{
    f4 a = *(const f4*)&yf_in[row * 64 + c4];
    a += *(const f4*)&bout[c4];
    #pragma unroll
    for (int sp = 0; sp < 16; ++sp)
        a += *(const f4*)&dl_in[sp * 65536 + row * 64 + c4];
    *(f4*)&yf_out[row * 64 + c4] = a;
    *(f4*)&out[row * 8192 + (t - 1) * 64 + c4] = a;
    _Float16 hi4[4], lo4[4];
    #pragma unroll
    for (int x = 0; x < 4; ++x) {
        hi4[x] = (_Float16)a[x];
        lo4[x] = (_Float16)(a[x] - (float)hi4[x]);
    }
    *(u32x2*)&yh_out[row * 64 + c4] = *(u32x2*)hi4;
    *(u32x2*)&yl_out[row * 64 + c4] = *(u32x2*)lo4;
}

extern "C" __global__ void __launch_bounds__(512, 2) k_step(
    int t,
    const _Float16* __restrict__ Wcat,         // [2048][576] fp16 (A or B variant)
    const float* __restrict__ bias,            // [2048]
    const _Float16* __restrict__ Wout,         // [64][512] fp16
    const float* __restrict__ bout,            // [64]
    const _Float16* __restrict__ hh_in, const _Float16* __restrict__ hl_in,  // [1024][512]
    _Float16* __restrict__ hh_out, _Float16* __restrict__ hl_out,
    float* __restrict__ cst,                   // [1024][512] fp32 (in-place)
    const float* __restrict__ yf_in, float* __restrict__ yf_out,             // [1024][64]
    const _Float16* __restrict__ yh_in, _Float16* __restrict__ yh_out,
    const _Float16* __restrict__ yl_in, _Float16* __restrict__ yl_out,
    const float* __restrict__ dl_in, float* __restrict__ dl_out,             // [16][1024][64]
    float* __restrict__ out)                   // [1024][128][64]
{
    __shared__ __align__(16) unsigned char smem[61440];
    _Float16* sAh = (_Float16*)smem;                             // [64][LDAH] = 25,600 B
    _Float16* sAl = (_Float16*)(smem + 25600);                   // [64][LDAH] = 25,600 B
    float*    sEx = (float*)smem;                                // overlay: [4][64][EXS] = 36,864 B
    _Float16* sHh = (_Float16*)(smem + 51200);                   // [64][HSTR] = 5,120 B
    _Float16* sHl = (_Float16*)(smem + 56320);                   // [64][HSTR]

    const int tid = threadIdx.x;
    const int bx  = blockIdx.x;
    const int mt  = bx >> 4, s = bx & 15;
    const int m0  = mt * 64, j0 = s * 32;

    if (t >= 128) {                                  // final launch: resolve y_127 only
        if (tid < 64) {
            int row = m0 + s * 4 + (tid >> 4);
            int c4  = (tid & 15) * 4;
            resolve_y(t, row, c4, yf_in, yf_out, dl_in, bout, yh_out, yl_out, out);
        }
        return;
    }

    const int w = tid >> 6, lane = tid & 63, l15 = lane & 15, quad = lane >> 4;
    const int quad8 = quad * 8;
    const int q = w >> 1, hx = w & 1;                // gate quadrant, col-half

    // ---- head prefetches (consumed post-GEMM; L3 latency hidden under GEMM) ----
    const int cm = tid >> 3, cjb = (tid & 7) * 4;    // cell mapping: row cm, 4 cols at cjb
    const int cjcol = j0 + cjb;
    const int ccrow = (m0 + cm) * 512 + cjcol;
    f4 cpre = *(const f4*)&cst[ccrow];
    f4 bi0 = *(const f4*)&bias[       cjcol];
    f4 bi1 = *(const f4*)&bias[ 512 + cjcol];
    f4 bi2 = *(const f4*)&bias[1024 + cjcol];
    f4 bi3 = *(const f4*)&bias[1536 + cjcol];
    const int dn = w >> 1, ap = w & 1;               // delta: out-col tile, m-half
    half8 bw = *(const half8*)&Wout[(dn * 16 + l15) * 512 + j0 + quad8];

    const int brow = (q * 512 + j0 + hx * 16 + l15) * 576;

    // ---- chunk-0 B prefetch (reg double-buffer) ----
    half8 bv[2][6];
    #pragma unroll
    for (int kc = 0; kc < 6; ++kc)
        bv[0][kc] = *(const half8*)&Wcat[brow + kc * 32 + quad8];

    // per-thread staging coordinates: 3 x 16B x 2 streams covers 64 rows x 192 halves
    int rr[3], cc3[3];
    #pragma unroll
    for (int it = 0; it < 3; ++it) {
        int i4 = it * 512 + tid;
        rr[it]  = i4 / 24;
        cc3[it] = (i4 % 24) * 8;
    }

    // ---- prologue: stage chunk 0 (B-cols 0..191: y part + h[0..127]) ----
    #pragma unroll
    for (int it = 0; it < 3; ++it) {
        int r = rr[it], cc = cc3[it];
        const _Float16 *sh, *sl;
        if (cc < 64) { sh = &yh_in[(m0 + r) * 64 + cc];         sl = &yl_in[(m0 + r) * 64 + cc]; }
        else         { sh = &hh_in[(m0 + r) * 512 + (cc - 64)]; sl = &hl_in[(m0 + r) * 512 + (cc - 64)]; }
        *(u32x4*)&sAh[r * LDAH + cc] = *(const u32x4*)sh;
        *(u32x4*)&sAl[r * LDAH + cc] = *(const u32x4*)sl;
    }

    f4 zero = {0.0f, 0.0f, 0.0f, 0.0f};
    f4 acc[4];
    acc[0] = zero; acc[1] = zero; acc[2] = zero; acc[3] = zero;

    // ---- 3 chunks of 192 B-cols; B reg-double-buffered, A staged T14-style ----
    u32x4 regH[3], regL[3];
    #pragma unroll
    for (int ch = 0; ch < 3; ++ch) {
        if (ch < 2) {
            #pragma unroll
            for (int it = 0; it < 3; ++it) {         // next chunk A (pure h stream)
                int c = (ch + 1) * 192 + cc3[it] - 64;
                regH[it] = *(const u32x4*)&hh_in[(m0 + rr[it]) * 512 + c];
                regL[it] = *(const u32x4*)&hl_in[(m0 + rr[it]) * 512 + c];
            }
            #pragma unroll
            for (int kc = 0; kc < 6; ++kc)           // next chunk B
                bv[(ch + 1) & 1][kc] = *(const half8*)&Wcat[brow + (ch + 1) * 192 + kc * 32 + quad8];
        }
        __syncthreads();                             // this chunk's LDS writes visible
        #pragma unroll
        for (int kc = 0; kc < 6; ++kc) {
            int kq = kc * 32 + quad8;
            half8 b = bv[ch & 1][kc];
            #pragma unroll
            for (int a = 0; a < 4; ++a) {
                half8 ah = *(const half8*)&sAh[(l15 + a * 16) * LDAH + kq];
                acc[a] = __builtin_amdgcn_mfma_f32_16x16x32_f16(ah, b, acc[a], 0, 0, 0);
            }
            #pragma unroll
            for (int a = 0; a < 4; ++a) {
                half8 al = *(const half8*)&sAl[(l15 + a * 16) * LDAH + kq];
                acc[a] = __builtin_amdgcn_mfma_f32_16x16x32_f16(al, b, acc[a], 0, 0, 0);
            }
        }
        if (ch < 2) {
            __syncthreads();                         // all reads of sA done
            #pragma unroll
            for (int it = 0; it < 3; ++it) {         // write-late half of T14 split
                *(u32x4*)&sAh[rr[it] * LDAH + cc3[it]] = regH[it];
                *(u32x4*)&sAl[rr[it] * LDAH + cc3[it]] = regL[it];
            }
        }
    }
    __syncthreads();                                 // sA dead -> overlay exchange

    // ---- gate exchange: D layout col=lane&15 (gate col), row=quad*4+reg (m) ----
    #pragma unroll
    for (int a = 0; a < 4; ++a)
        #pragma unroll
        for (int r = 0; r < 4; ++r)
            sEx[(q * 64 + a * 16 + quad * 4 + r) * EXS + hx * 16 + l15] = acc[a][r];
    __syncthreads();

    // ---- LSTM cell update: thread -> row cm, 4 h-cols at cjb ----
    {
        f4 c0 = cpre;
        f4 gI = *(const f4*)&sEx[(0 * 64 + cm) * EXS + cjb];
        f4 gF = *(const f4*)&sEx[(1 * 64 + cm) * EXS + cjb];
        f4 gG = *(const f4*)&sEx[(2 * 64 + cm) * EXS + cjb];
        f4 gO = *(const f4*)&sEx[(3 * 64 + cm) * EXS + cjb];
        _Float16 hi4[4], lo4[4];
        #pragma unroll
        for (int x = 0; x < 4; ++x) {
            float iv = sigm(gI[x] + bi0[x]);
            float fv = sigm(gF[x] + bi1[x]);
            float gv = tanh_(gG[x] + bi2[x]);
            float ov = sigm(gO[x] + bi3[x]);
            float cn = fv * c0[x] + iv * gv;
            float hn = ov * tanh_(cn);
            c0[x] = cn;
            _Float16 hi = (_Float16)hn;
            hi4[x] = hi;
            lo4[x] = (_Float16)(hn - (float)hi);
        }
        *(f4*)&cst[ccrow] = c0;
        *(u32x2*)&hh_out[ccrow]        = *(u32x2*)hi4;
        *(u32x2*)&hl_out[ccrow]        = *(u32x2*)lo4;
        *(u32x2*)&sHh[cm * HSTR + cjb] = *(u32x2*)hi4;
        *(u32x2*)&sHl[cm * HSTR + cjb] = *(u32x2*)lo4;
    }
    __syncthreads();

    // ---- Delta partial: dl_out[s] = (h_hi+h_lo)(strip) @ Wout^T ----
    // wave (dn, ap): out-col tile dn, m-tiles ap*2..ap*2+1
    {
        f4 d[2];
        d[0] = zero; d[1] = zero;
        #pragma unroll
        for (int a2 = 0; a2 < 2; ++a2) {
            int a = ap * 2 + a2;
            half8 ahh = *(const half8*)&sHh[(a * 16 + l15) * HSTR + quad8];
            half8 ahl = *(const half8*)&sHl[(a * 16 + l15) * HSTR + quad8];
            d[a2] = __builtin_amdgcn_mfma_f32_16x16x32_f16(ahh, bw, d[a2], 0, 0, 0);
            d[a2] = __builtin_amdgcn_mfma_f32_16x16x32_f16(ahl, bw, d[a2], 0, 0, 0);
        }
        #pragma unroll
        for (int a2 = 0; a2 < 2; ++a2) {
            int a = ap * 2 + a2;
            #pragma unroll
            for (int r = 0; r < 4; ++r)
                dl_out[s * 65536 + (m0 + a * 16 + quad * 4 + r) * 64 + dn * 16 + l15] = d[a2][r];
        }
    }

    // ---- tail resolve of y_{t-1} (no dependency on this step's compute) ----
    if (t >= 1 && tid < 64) {
        int row = m0 + s * 4 + (tid >> 4);
        int c4  = (tid & 15) * 4;
        resolve_y(t, row, c4, yf_in, yf_out, dl_in, bout, yh_out, yl_out, out);
    }
}

// ---------------- host ----------------
extern "C" void kernel_launch(void* const* d_in, const int* in_sizes, int n_in,
                              void* d_out, int out_size, void* d_ws, size_t ws_size,
                              hipStream_t stream)
{
    const float* z   = (const float*)d_in[0];
    const float* x   = (const float*)d_in[1];
    const float* Wih = (const float*)d_in[2];
    const float* Whh = (const float*)d_in[3];
    const float* bih = (const float*)d_in[4];
    const float* bhh = (const float*)d_in[5];
    const float* Wp  = (const float*)d_in[6];
    const float* bp  = (const float*)d_in[7];
    const float* Wo  = (const float*)d_in[8];
    const float* bo  = (const float*)d_in[9];

    char* w = (char*)d_ws;
    _Float16* WA  = (_Float16*)w; w += 2359296;   // [2048][576] fp16
    _Float16* WB  = (_Float16*)w; w += 2359296;
    _Float16* WoB = (_Float16*)w; w += 65536;     // [64][512] fp16
    float* b0v = (float*)w; w += 8192;
    float* b1v = (float*)w; w += 8192;
    _Float16* hh[2];
    hh[0] = (_Float16*)w; w += 1048576;
    hh[1] = (_Float16*)w; w += 1048576;
    _Float16* hl[2];
    hl[0] = (_Float16*)w; w += 1048576;
    hl[1] = (_Float16*)w; w += 1048576;
    float* cst = (float*)w; w += 2097152;
    float* yf[2];
    yf[0] = (float*)w; w += 262144;
    yf[1] = (float*)w; w += 262144;
    _Float16* yh[2];
    yh[0] = (_Float16*)w; w += 131072;
    yh[1] = (_Float16*)w; w += 131072;
    _Float16* yl[2];
    yl[0] = (_Float16*)w; w += 131072;
    yl[1] = (_Float16*)w; w += 131072;
    float* dl[2];
    dl[0] = (float*)w; w += 4194304;              // [16][1024][64] fp32
    dl[1] = (float*)w; w += 4194304;
    float* out = (float*)d_out;

    k_wcat<<<4608, 256, 0, stream>>>(Wih, Whh, WA, WB);
    k_comb<<<4096, 256, 0, stream>>>(Wih, Whh, Wo, WB);
    k_misc<<<392, 256, 0, stream>>>(Wo, bih, bhh, Wih, bo, x, WoB, b0v, b1v,
                                    yf[0], yf[1], yh[0], yh[1], yl[0], yl[1]);
    k_h0<<<2048, 256, 0, stream>>>(z, Wp, bp, cst, hh[0], hl[0]);

    for (int t = 0; t <= 128; ++t) {
        k_step<<<256, 512, 0, stream>>>(t,
            (t == 0) ? WA : WB, (t == 0) ? b0v : b1v,
            WoB, bo,
            hh[t & 1], hl[t & 1], hh[(t + 1) & 1], hl[(t + 1) & 1],
            cst,
            yf[t & 1], yf[(t + 1) & 1],
            yh[t & 1], yh[(t + 1) & 1],
            yl[t & 1], yl[(t + 1) & 1],
            dl[(t + 1) & 1], dl[t & 1],
            out);
    }
}